// Round 6
// baseline (66.958 us; speedup 1.0000x reference)
//
#include <hip/hip_runtime.h>
#include <hip/hip_bf16.h>

constexpr int HID = 1024;
constexpr int KD  = 16;    // probe directions
constexpr int NT  = 512;   // threads per block (8 waves)
constexpr int NW  = 8;     // waves per block
constexpr int TM  = 16;    // rows per tile

typedef short bf16x8 __attribute__((ext_vector_type(8)));   // MFMA A/B frag
typedef float f32x4  __attribute__((ext_vector_type(4)));   // MFMA C/D frag

__device__ __forceinline__ short f2b(float x) {
    __hip_bfloat16 b = __float2bfloat16(x);
    return *reinterpret_cast<short*>(&b);
}

// All global I/O is fully coalesced; LDS does layout conversion to/from MFMA
// fragment order. LDS caps residency at 2 blocks/CU (= 4 waves/SIMD), so we
// pin waves_per_eu to exactly 4: VGPR budget 128, which fits the persistent
// Q fragments (48 VGPRs) + loop live set WITHOUT scratch spills. (Round-5
// failure mode: allocator clamped to 64 VGPRs chasing 8 waves/EU that LDS
// forbids anyway -> aq[] spilled -> ~34 MB scratch writes + epilogue stalls.)
__global__ __attribute__((amdgpu_waves_per_eu(4, 4))) __launch_bounds__(NT)
void probe_removal_mfma3(const float* __restrict__ H,
                         const float* __restrict__ Qf,
                         float* __restrict__ out,
                         int ntiles)
{
    const int t    = threadIdx.x;
    const int lane = t & 63;
    const int w    = t >> 6;       // wave: owns hidden-slice [w*128, w*128+128)
    const int r    = lane & 15;
    const int q    = lane >> 4;

    __shared__ __align__(16) unsigned short Ht[TM][HID];     // 32 KB, swizzled bf16 H tile
    __shared__ __align__(16) float red[NW][TM][20];          // coef partials [wave][row][dir]
    __shared__ float s2red[NW][TM];                          // ||h||^2 partials
    __shared__ __align__(16) float outl[TM][NW*68 + 4];      // 35 KB out staging (row stride 548)

    char* HtB = reinterpret_cast<char*>(&Ht[0][0]);

    // ---------- Q fragments (register-resident, loaded once) ----------
    // coef GEMM B-frag: B[k][n=dir=r], k = w*128+kt*32+q*8+i
    bf16x8 bq[4];
    #pragma unroll
    for (int kt = 0; kt < 4; ++kt)
        #pragma unroll
        for (int i = 0; i < 8; ++i)
            bq[kt][i] = f2b(Qf[(w*128 + kt*32 + q*8 + i)*KD + r]);
    // epilogue GEMM A-frag: A[m=col=r][k=dir(pad to 32)]
    bf16x8 aq[8];
    #pragma unroll
    for (int j = 0; j < 8; ++j) {
        if (q < 2) {
            const float* src = Qf + (w*128 + j*16 + r)*KD + q*8;
            const float4 x = *reinterpret_cast<const float4*>(src);
            const float4 y = *reinterpret_cast<const float4*>(src + 4);
            aq[j][0]=f2b(x.x); aq[j][1]=f2b(x.y); aq[j][2]=f2b(x.z); aq[j][3]=f2b(x.w);
            aq[j][4]=f2b(y.x); aq[j][5]=f2b(y.y); aq[j][6]=f2b(y.z); aq[j][7]=f2b(y.w);
        } else {
            #pragma unroll
            for (int i = 0; i < 8; ++i) aq[j][i] = 0;
        }
    }

    for (int tile = blockIdx.x; tile < ntiles; tile += gridDim.x) {
        const float* Hbase = H + (size_t)tile*TM*HID;

        // ---- L: coalesced global load -> bf16 -> swizzled LDS ----
        #pragma unroll
        for (int j = 0; j < 8; ++j) {
            const int f4 = t + j*NT;                 // float4 idx in tile, wave-contiguous
            const float4 v = reinterpret_cast<const float4*>(Hbase)[f4];
            const int rr  = f4 >> 8;                 // row (256 float4/row)
            const int c4  = f4 & 255;
            const int c16 = c4 >> 1, half = c4 & 1;  // 16B chunk + 8B half
            short4 b;
            b.x = f2b(v.x); b.y = f2b(v.y); b.z = f2b(v.z); b.w = f2b(v.w);
            *reinterpret_cast<short4*>(HtB + rr*2048 + ((c16 ^ (rr & 7))*16) + half*8) = b;
        }
        __syncthreads();   // b1

        // ---- C: A-frags from LDS, coef MFMA, ||h||^2 in VALU from bf16 ----
        bf16x8 af[4];
        #pragma unroll
        for (int kt = 0; kt < 4; ++kt) {
            const int c16 = w*16 + kt*4 + q;
            af[kt] = *reinterpret_cast<const bf16x8*>(HtB + r*2048 + ((c16 ^ (r & 7))*16));
        }
        f32x4 acc = {0.f, 0.f, 0.f, 0.f};
        #pragma unroll
        for (int kt = 0; kt < 4; ++kt)
            acc = __builtin_amdgcn_mfma_f32_16x16x32_bf16(af[kt], bq[kt], acc, 0, 0, 0);

        float s2 = 0.f;
        #pragma unroll
        for (int kt = 0; kt < 4; ++kt) {
            const uint4 u = __builtin_bit_cast(uint4, af[kt]);
            #pragma unroll
            for (int e = 0; e < 4; ++e) {
                const unsigned int ue = (&u.x)[e];
                const float lo = __uint_as_float(ue << 16);
                const float hi = __uint_as_float(ue & 0xffff0000u);
                s2 = fmaf(lo, lo, fmaf(hi, hi, s2));
            }
        }
        s2 += __shfl_xor(s2, 16);
        s2 += __shfl_xor(s2, 32);

        #pragma unroll
        for (int i = 0; i < 4; ++i) red[w][q*4 + i][r] = acc[i];   // C[m=q*4+i][n=dir=r]
        if (q == 0) s2red[w][r] = s2;
        __syncthreads();   // b2

        // ---- R: cross-wave reduce -> coefs, scale, pb frag ----
        float cf[8] = {0,0,0,0,0,0,0,0};
        if (q < 2) {
            #pragma unroll
            for (int w2 = 0; w2 < NW; ++w2) {
                const float4 a  = *reinterpret_cast<const float4*>(&red[w2][r][q*8]);
                const float4 bb = *reinterpret_cast<const float4*>(&red[w2][r][q*8 + 4]);
                cf[0]+=a.x;  cf[1]+=a.y;  cf[2]+=a.z;  cf[3]+=a.w;
                cf[4]+=bb.x; cf[5]+=bb.y; cf[6]+=bb.z; cf[7]+=bb.w;
            }
        }
        float s2tot = 0.f;
        #pragma unroll
        for (int w2 = 0; w2 < NW; ++w2) s2tot += s2red[w2][r];   // broadcast reads

        float sc2 = 0.f;
        #pragma unroll
        for (int i = 0; i < 8; ++i) sc2 = fmaf(cf[i], cf[i], sc2);
        sc2 += __shfl_xor(sc2, 16);
        sc2 += __shfl_xor(sc2, 32);
        const float scale = rsqrtf(fmaxf(1.0f - sc2 / s2tot, 1e-20f));

        bf16x8 pb;   // B[k=dir][n=row=r]; q>=2 lanes hold K-pad zeros
        #pragma unroll
        for (int i = 0; i < 8; ++i) pb[i] = f2b(cf[i]);

        // ---- E+S: two half passes (epilogue MFMA -> outl -> coalesced store) ----
        const f32x4 zero4 = {0.f, 0.f, 0.f, 0.f};
        #pragma unroll
        for (int pass = 0; pass < 2; ++pass) {
            #pragma unroll
            for (int jj = 0; jj < 4; ++jj) {
                const int j = pass*4 + jj;
                f32x4 d = __builtin_amdgcn_mfma_f32_16x16x32_bf16(aq[j], pb, zero4, 0, 0, 0);
                // h (bf16) re-read from LDS at the C-layout positions
                const int c16 = w*16 + j*2 + (q >> 1);
                const uint2 hu = *reinterpret_cast<const uint2*>(
                    HtB + r*2048 + ((c16 ^ (r & 7))*16) + (q & 1)*8);
                f32x4 o;
                o[0] = (__uint_as_float(hu.x << 16)         - d[0]) * scale;
                o[1] = (__uint_as_float(hu.x & 0xffff0000u) - d[1]) * scale;
                o[2] = (__uint_as_float(hu.y << 16)         - d[2]) * scale;
                o[3] = (__uint_as_float(hu.y & 0xffff0000u) - d[3]) * scale;
                *reinterpret_cast<f32x4*>(&outl[r][w*68 + jj*16 + q*4]) = o;
            }
            __syncthreads();   // outl ready

            // coalesced store of this half: full 128B lines only
            #pragma unroll
            for (int p = 0; p < 4; ++p) {
                const int flat = t + p*NT;           // float4 idx in half-tile
                const int rr  = flat >> 7;
                const int idx = flat & 127;
                const int ww  = idx >> 4, i4 = idx & 15;
                const float4 v = *reinterpret_cast<const float4*>(&outl[rr][ww*68 + i4*4]);
                const f32x4 vv = {v.x, v.y, v.z, v.w};
                float* dst = out + ((size_t)tile*TM + rr)*HID + ww*128 + pass*64 + i4*4;
                __builtin_nontemporal_store(vv, reinterpret_cast<f32x4*>(dst));
            }
            if (pass == 0) __syncthreads();   // outl free for pass 1
            // (post-pass-1 barrier removed: next tile's b1 already orders
            //  this tile's outl reads before next tile's outl writes, and all
            //  Ht reads completed before the pass-1 "outl ready" barrier)
        }
    }
}

extern "C" void kernel_launch(void* const* d_in, const int* in_sizes, int n_in,
                              void* d_out, int out_size, void* d_ws, size_t ws_size,
                              hipStream_t stream) {
    const float* H  = (const float*)d_in[0];   // [8,4096,1024] f32
    const float* Qf = (const float*)d_in[1];   // [1024,16] f32, orthonormal cols
    float* outp     = (float*)d_out;
    const int nrows  = in_sizes[0] / HID;      // 32768
    const int ntiles = nrows / TM;             // 2048

    dim3 grid(512), block(NT);                 // 2 blocks/CU resident, 4 tiles/block
    hipLaunchKernelGGL(probe_removal_mfma3, grid, block, 0, stream,
                       H, Qf, outp, ntiles);
}

// Round 7
// 66.285 us; speedup vs baseline: 1.0102x; 1.0102x over previous
//
#include <hip/hip_runtime.h>
#include <hip/hip_bf16.h>

constexpr int HID = 1024;
constexpr int KD  = 16;    // probe directions
constexpr int NT  = 512;   // threads per block (8 waves)
constexpr int NW  = 8;     // waves per block
constexpr int TM  = 16;    // rows per tile

typedef short bf16x8 __attribute__((ext_vector_type(8)));   // MFMA A/B frag
typedef float f32x4  __attribute__((ext_vector_type(4)));   // MFMA C/D frag

__device__ __forceinline__ short f2b(float x) {
    __hip_bfloat16 b = __float2bfloat16(x);
    return *reinterpret_cast<short*>(&b);
}

// All global I/O fully coalesced; LDS converts layouts to/from MFMA fragment
// order. Round-6 diagnosis: persistent aq[8] (32 VGPRs) was spilled to scratch
// at the 64-VGPR clamp -> exactly 32 MiB excess HBM writes (spill store) +
// scratch reloads on the epilogue critical path. Fix: no persistent aq --
// epilogue Q-fragments are loaded per-use from L2-hot Qf (64 KB) with inline
// bf16 convert; an asm-launder of the Q pointer inside the tile loop blocks
// LICM from hoisting them back into persistent registers.
__global__ __launch_bounds__(NT)
void probe_removal_mfma4(const float* __restrict__ H,
                         const float* __restrict__ Qf,
                         float* __restrict__ out,
                         int ntiles)
{
    const int t    = threadIdx.x;
    const int lane = t & 63;
    const int w    = t >> 6;       // wave: owns hidden-slice [w*128, w*128+128)
    const int r    = lane & 15;
    const int q    = lane >> 4;

    __shared__ __align__(16) unsigned short Ht[TM][HID];     // 32 KB, swizzled bf16 H tile
    __shared__ __align__(16) float red[NW][TM][20];          // coef partials [wave][row][dir]
    __shared__ float s2red[NW][TM];                          // ||h||^2 partials
    __shared__ __align__(16) float outl[TM][NW*68 + 4];      // 35 KB out staging (row stride 548)

    char* HtB = reinterpret_cast<char*>(&Ht[0][0]);

    // ---------- coef GEMM B-frag (the ONLY persistent fragment, 16 VGPRs) ----------
    // B[k][n=dir=r], k = w*128+kt*32+q*8+i
    bf16x8 bq[4];
    #pragma unroll
    for (int kt = 0; kt < 4; ++kt)
        #pragma unroll
        for (int i = 0; i < 8; ++i)
            bq[kt][i] = f2b(Qf[(w*128 + kt*32 + q*8 + i)*KD + r]);

    for (int tile = blockIdx.x; tile < ntiles; tile += gridDim.x) {
        const float* Hbase = H + (size_t)tile*TM*HID;

        // launder Qf so the per-use epilogue Q loads below are NOT
        // loop-invariant (LICM would hoist them into 32 persistent regs
        // and re-create the round-5/6 scratch spill)
        const float* Qv = Qf;
        asm volatile("" : "+s"(Qv));

        // ---- L: coalesced global load -> bf16 -> swizzled LDS ----
        #pragma unroll
        for (int j = 0; j < 8; ++j) {
            const int f4 = t + j*NT;                 // float4 idx in tile, wave-contiguous
            const float4 v = reinterpret_cast<const float4*>(Hbase)[f4];
            const int rr  = f4 >> 8;                 // row (256 float4/row)
            const int c4  = f4 & 255;
            const int c16 = c4 >> 1, half = c4 & 1;  // 16B chunk + 8B half
            short4 b;
            b.x = f2b(v.x); b.y = f2b(v.y); b.z = f2b(v.z); b.w = f2b(v.w);
            *reinterpret_cast<short4*>(HtB + rr*2048 + ((c16 ^ (rr & 7))*16) + half*8) = b;
        }
        __syncthreads();   // b1

        // ---- C: A-frags from LDS, coef MFMA, ||h||^2 in VALU from bf16 ----
        bf16x8 af[4];
        #pragma unroll
        for (int kt = 0; kt < 4; ++kt) {
            const int c16 = w*16 + kt*4 + q;
            af[kt] = *reinterpret_cast<const bf16x8*>(HtB + r*2048 + ((c16 ^ (r & 7))*16));
        }
        f32x4 acc = {0.f, 0.f, 0.f, 0.f};
        #pragma unroll
        for (int kt = 0; kt < 4; ++kt)
            acc = __builtin_amdgcn_mfma_f32_16x16x32_bf16(af[kt], bq[kt], acc, 0, 0, 0);

        float s2 = 0.f;
        #pragma unroll
        for (int kt = 0; kt < 4; ++kt) {
            const uint4 u = __builtin_bit_cast(uint4, af[kt]);
            #pragma unroll
            for (int e = 0; e < 4; ++e) {
                const unsigned int ue = (&u.x)[e];
                const float lo = __uint_as_float(ue << 16);
                const float hi = __uint_as_float(ue & 0xffff0000u);
                s2 = fmaf(lo, lo, fmaf(hi, hi, s2));
            }
        }
        s2 += __shfl_xor(s2, 16);
        s2 += __shfl_xor(s2, 32);

        #pragma unroll
        for (int i = 0; i < 4; ++i) red[w][q*4 + i][r] = acc[i];   // C[m=q*4+i][n=dir=r]
        if (q == 0) s2red[w][r] = s2;
        __syncthreads();   // b2

        // ---- R: cross-wave reduce -> coefs, scale, pb frag ----
        float cf[8] = {0,0,0,0,0,0,0,0};
        if (q < 2) {
            #pragma unroll
            for (int w2 = 0; w2 < NW; ++w2) {
                const float4 a  = *reinterpret_cast<const float4*>(&red[w2][r][q*8]);
                const float4 bb = *reinterpret_cast<const float4*>(&red[w2][r][q*8 + 4]);
                cf[0]+=a.x;  cf[1]+=a.y;  cf[2]+=a.z;  cf[3]+=a.w;
                cf[4]+=bb.x; cf[5]+=bb.y; cf[6]+=bb.z; cf[7]+=bb.w;
            }
        }
        float s2tot = 0.f;
        #pragma unroll
        for (int w2 = 0; w2 < NW; ++w2) s2tot += s2red[w2][r];   // broadcast reads

        float sc2 = 0.f;
        #pragma unroll
        for (int i = 0; i < 8; ++i) sc2 = fmaf(cf[i], cf[i], sc2);
        sc2 += __shfl_xor(sc2, 16);
        sc2 += __shfl_xor(sc2, 32);
        const float scale = rsqrtf(fmaxf(1.0f - sc2 / s2tot, 1e-20f));

        bf16x8 pb;   // B[k=dir][n=row=r]; q>=2 lanes hold K-pad zeros
        #pragma unroll
        for (int i = 0; i < 8; ++i) pb[i] = f2b(cf[i]);

        // ---- E+S: two half passes (epilogue MFMA -> outl -> coalesced store) ----
        const f32x4 zero4 = {0.f, 0.f, 0.f, 0.f};
        #pragma unroll
        for (int pass = 0; pass < 2; ++pass) {
            #pragma unroll
            for (int jj = 0; jj < 4; ++jj) {
                const int j = pass*4 + jj;
                // epilogue A-frag per-use from L2-hot Qf: A[m=col=r][k=dir pad32]
                bf16x8 aqj;
                if (q < 2) {
                    const float* src = Qv + (w*128 + j*16 + r)*KD + q*8;
                    const float4 x = *reinterpret_cast<const float4*>(src);
                    const float4 y = *reinterpret_cast<const float4*>(src + 4);
                    aqj[0]=f2b(x.x); aqj[1]=f2b(x.y); aqj[2]=f2b(x.z); aqj[3]=f2b(x.w);
                    aqj[4]=f2b(y.x); aqj[5]=f2b(y.y); aqj[6]=f2b(y.z); aqj[7]=f2b(y.w);
                } else {
                    #pragma unroll
                    for (int i = 0; i < 8; ++i) aqj[i] = 0;
                }
                f32x4 d = __builtin_amdgcn_mfma_f32_16x16x32_bf16(aqj, pb, zero4, 0, 0, 0);
                // h (bf16) re-read from LDS at the C-layout positions
                const int c16 = w*16 + j*2 + (q >> 1);
                const uint2 hu = *reinterpret_cast<const uint2*>(
                    HtB + r*2048 + ((c16 ^ (r & 7))*16) + (q & 1)*8);
                f32x4 o;
                o[0] = (__uint_as_float(hu.x << 16)         - d[0]) * scale;
                o[1] = (__uint_as_float(hu.x & 0xffff0000u) - d[1]) * scale;
                o[2] = (__uint_as_float(hu.y << 16)         - d[2]) * scale;
                o[3] = (__uint_as_float(hu.y & 0xffff0000u) - d[3]) * scale;
                *reinterpret_cast<f32x4*>(&outl[r][w*68 + jj*16 + q*4]) = o;
            }
            __syncthreads();   // outl ready

            // coalesced store of this half: full 128B lines only
            #pragma unroll
            for (int p = 0; p < 4; ++p) {
                const int flat = t + p*NT;           // float4 idx in half-tile
                const int rr  = flat >> 7;
                const int idx = flat & 127;
                const int ww  = idx >> 4, i4 = idx & 15;
                const float4 v = *reinterpret_cast<const float4*>(&outl[rr][ww*68 + i4*4]);
                const f32x4 vv = {v.x, v.y, v.z, v.w};
                float* dst = out + ((size_t)tile*TM + rr)*HID + ww*128 + pass*64 + i4*4;
                __builtin_nontemporal_store(vv, reinterpret_cast<f32x4*>(dst));
            }
            if (pass == 0) __syncthreads();   // outl free for pass 1
            // (post-pass-1 barrier elided: next tile's b1 orders outl reuse)
        }
    }
}

extern "C" void kernel_launch(void* const* d_in, const int* in_sizes, int n_in,
                              void* d_out, int out_size, void* d_ws, size_t ws_size,
                              hipStream_t stream) {
    const float* H  = (const float*)d_in[0];   // [8,4096,1024] f32
    const float* Qf = (const float*)d_in[1];   // [1024,16] f32, orthonormal cols
    float* outp     = (float*)d_out;
    const int nrows  = in_sizes[0] / HID;      // 32768
    const int ntiles = nrows / TM;             // 2048

    dim3 grid(512), block(NT);                 // 2 blocks/CU resident, 4 tiles/block
    hipLaunchKernelGGL(probe_removal_mfma4, grid, block, 0, stream,
                       H, Qf, outp, ntiles);
}